// Round 9
// baseline (389.346 us; speedup 1.0000x reference)
//
#include <hip/hip_runtime.h>

typedef _Float16 f16_t;
typedef _Float16 f16x8 __attribute__((ext_vector_type(8)));
typedef float    f32x4 __attribute__((ext_vector_type(4)));

#define DIMD 512
#define KCB  1024
#define TT   2048
#define BB   16
#define NTOT (BB*TT)                   // 32768
#define OUT_IDX  (BB*DIMD*TT)          // 16777216
#define OUT_LOSS (OUT_IDX + NTOT)
#define TAU 3.0e-4f
// score = w2[k] - 2*dot; fast dot computed on (z, 1024*w) -> scale back by 2^-10
#define NEG2_SCALE (-0.001953125f)     // -2/1024, exact

__device__ __forceinline__ void gll16(const f16_t* g, f16_t* l) {
    __builtin_amdgcn_global_load_lds(
        (const __attribute__((address_space(1))) unsigned int*)g,
        (__attribute__((address_space(3))) unsigned int*)l, 16, 0, 0);
}

// ---------- prep: wf16[k][d] = f16(1024*cb), w2[k] = fl32(fp64 sum fl32(cb^2)),
// ----------       cbT[d][k] = cb[k][d]  (fp32 transposed codebook for recheck) ----------
__global__ __launch_bounds__(256) void prep_kernel(const float* __restrict__ cb,
                                                   f16_t* __restrict__ wf,
                                                   float* __restrict__ w2,
                                                   float* __restrict__ cbT) {
    const int wave = threadIdx.x >> 6, lane = threadIdx.x & 63;
    const int row  = blockIdx.x * 4 + wave;
    const float* src = cb + (size_t)row * DIMD + lane * 8;
    float4 v0 = *(const float4*)(src);
    float4 v1 = *(const float4*)(src + 4);
    f16x8 o;
    o[0] = (f16_t)(v0.x * 1024.f); o[1] = (f16_t)(v0.y * 1024.f);
    o[2] = (f16_t)(v0.z * 1024.f); o[3] = (f16_t)(v0.w * 1024.f);
    o[4] = (f16_t)(v1.x * 1024.f); o[5] = (f16_t)(v1.y * 1024.f);
    o[6] = (f16_t)(v1.z * 1024.f); o[7] = (f16_t)(v1.w * 1024.f);
    *(f16x8*)(wf + (size_t)row * DIMD + lane * 8) = o;
    // transposed fp32 copy (scattered 4B stores; 2MB total, negligible)
    float vals[8] = {v0.x, v0.y, v0.z, v0.w, v1.x, v1.y, v1.z, v1.w};
    #pragma unroll
    for (int u = 0; u < 8; ++u)
        cbT[(size_t)(lane * 8 + u) * KCB + row] = vals[u];
    float s0 = v0.x * v0.x, s1 = v0.y * v0.y, s2 = v0.z * v0.z, s3 = v0.w * v0.w;
    float s4 = v1.x * v1.x, s5 = v1.y * v1.y, s6 = v1.z * v1.z, s7 = v1.w * v1.w;
    double s = (double)s0 + (double)s1 + (double)s2 + (double)s3 +
               (double)s4 + (double)s5 + (double)s6 + (double)s7;
    #pragma unroll
    for (int m = 1; m < 64; m <<= 1) s += __shfl_xor(s, m, 64);
    if (lane == 0) w2[row] = (float)s;
}

// ---------- transpose z -> token-major fp16; also z2[n] = sum_d z^2 ----------
// block = 64 tokens x full 512 d; wave w covers d in [w*128, w*128+128)
__global__ __launch_bounds__(256) void tsplit_kernel(const float* __restrict__ z,
                                                     f16_t* __restrict__ zf,
                                                     float* __restrict__ z2) {
    __shared__ float zred[4][64];
    const int tid  = threadIdx.x;
    const int wave = tid >> 6, lane = tid & 63;
    const int tok  = blockIdx.x * 64 + lane;
    const int b = tok >> 11, t = tok & 2047;
    const float* src = z + (size_t)b * DIMD * TT + t;
    const int d0 = wave * 128;
    double zp = 0.0;
    for (int j = 0; j < 16; ++j) {
        f16x8 o;
        #pragma unroll
        for (int u = 0; u < 8; ++u) {
            float v = src[(size_t)(d0 + j * 8 + u) * TT];
            o[u] = (f16_t)v;
            float vv = v * v;
            zp += (double)vv;
        }
        *(f16x8*)(zf + (size_t)tok * DIMD + d0 + j * 8) = o;
    }
    zred[wave][lane] = (float)zp;
    __syncthreads();
    if (wave == 0)
        z2[blockIdx.x * 64 + lane] =
            zred[0][lane] + zred[1][lane] + zred[2][lane] + zred[3][lane];
}

// ---------- fast argmin, m97 geometry: 128 tok x 128 codes per block,
// ----------  K-outer (8 x 64d), A+B staged per K-step (32KB LDS, ~3 blk/CU),
// ----------  4 waves with 64x64 tiles (4 af + 4 bf -> 16 MFMA per k-slice).
// ----------  Per-token partial (b1,b2,i1) written per code-tile; merged by
// ----------  fmerge_kernel in ascending tile order (associative two-min).
__global__ __launch_bounds__(256, 3) void fast_kernel(
    const f16_t* __restrict__ zf, const f16_t* __restrict__ wf,
    const float* __restrict__ w2,
    float* __restrict__ pb1, float* __restrict__ pb2, int* __restrict__ pi)
{
    __shared__ __align__(16) f16_t As[128 * 64];   // 16KB [tok][k] swizzled
    __shared__ __align__(16) f16_t Bs[128 * 64];   // 16KB [code][k] swizzled

    const int tid  = threadIdx.x;      // 0..255
    const int wave = tid >> 6;         // 0..3
    const int lane = tid & 63;
    const int m    = lane & 15;
    const int quad = lane >> 4;
    const int wr   = wave >> 1;        // token half (64)
    const int wc   = wave & 1;         // code half (64)

    // XCD-aware swizzle (2048 % 8 == 0 -> bijective): consecutive wg on one
    // XCD share the A m-tile -> A-tile L2-hits for 7 of 8 blocks.
    const int orig = blockIdx.x;
    const int wg   = (orig & 7) * 256 + (orig >> 3);
    const int mt_i = wg >> 3;          // 0..255  token tile
    const int nt_i = wg & 7;           // 0..7    code tile
    const int tok0  = mt_i * 128;
    const int code0 = nt_i * 128;

    // staging sources/dests: s = q*256+tid, row = s>>3, group g = s&7,
    // pre-swizzled source column gc = g ^ (row&7), linear LDS dest.
    const f16_t* gA[4]; const f16_t* gB[4]; f16_t* lA[4]; f16_t* lB[4];
    #pragma unroll
    for (int q = 0; q < 4; ++q) {
        int s = q * 256 + tid, row = s >> 3, gc = (s & 7) ^ (row & 7);
        gA[q] = zf + (size_t)(tok0 + row) * DIMD + gc * 8;
        gB[q] = wf + (size_t)(code0 + row) * DIMD + gc * 8;
        lA[q] = As + s * 8;
        lB[q] = Bs + s * 8;
    }

    f32x4 acc[4][4] = {};              // [mt][nt]

    for (int kt = 0; kt < 8; ++kt) {
        __syncthreads();               // tiles free to overwrite
        #pragma unroll
        for (int q = 0; q < 4; ++q) gll16(gA[q] + kt * 64, lA[q]);
        #pragma unroll
        for (int q = 0; q < 4; ++q) gll16(gB[q] + kt * 64, lB[q]);
        __syncthreads();               // drain staging
        #pragma unroll
        for (int kk = 0; kk < 2; ++kk) {   // d ascending: kk*32 within kt*64
            f16x8 af[4], bf[4];
            #pragma unroll
            for (int mt = 0; mt < 4; ++mt) {
                int row = wr * 64 + mt * 16 + m;
                af[mt] = *(const f16x8*)(As + row * 64 +
                                         (((kk * 4 + quad) ^ (row & 7)) * 8));
            }
            #pragma unroll
            for (int nt = 0; nt < 4; ++nt) {
                int row = wc * 64 + nt * 16 + m;
                bf[nt] = *(const f16x8*)(Bs + row * 64 +
                                         (((kk * 4 + quad) ^ (row & 7)) * 8));
            }
            #pragma unroll
            for (int mt = 0; mt < 4; ++mt)
                #pragma unroll
                for (int nt = 0; nt < 4; ++nt)
                    acc[mt][nt] = __builtin_amdgcn_mfma_f32_16x16x32_f16(
                        af[mt], bf[nt], acc[mt][nt], 0, 0, 0);
        }
    }

    // ---- tracker over this block's 128 codes (16 token-rows per lane) ----
    float b1[16], b2[16]; int i1[16];
    #pragma unroll
    for (int r = 0; r < 16; ++r) { b1[r] = 3.4e38f; b2[r] = 3.4e38f; i1[r] = 0; }
    #pragma unroll
    for (int nt = 0; nt < 4; ++nt) {
        const int col = code0 + wc * 64 + nt * 16 + m;
        const float w2c = w2[col];
        #pragma unroll
        for (int mt = 0; mt < 4; ++mt)
            #pragma unroll
            for (int r = 0; r < 4; ++r) {
                float s = fmaf(NEG2_SCALE, acc[mt][nt][r], w2c);
                const int ri = mt * 4 + r;
                if (s < b1[ri]) { b2[ri] = b1[ri]; b1[ri] = s; i1[ri] = col; }
                else if (s < b2[ri]) b2[ri] = s;
            }
    }

    // reduce over the 16 m-lanes (code dimension within fragment)
    #pragma unroll
    for (int msk = 1; msk < 16; msk <<= 1) {
        #pragma unroll
        for (int ri = 0; ri < 16; ++ri) {
            float o1 = __shfl_xor(b1[ri], msk, 64);
            int   oi = __shfl_xor(i1[ri], msk, 64);
            float o2 = __shfl_xor(b2[ri], msk, 64);
            if (o1 < b1[ri] || (o1 == b1[ri] && oi < i1[ri])) {
                b2[ri] = fminf(b1[ri], o2); b1[ri] = o1; i1[ri] = oi;
            } else {
                b2[ri] = fminf(b2[ri], o1);
            }
        }
    }

    // merge the two code-halves (wc) via LDS scratch (reuse As)
    __syncthreads();
    float* Lb1 = (float*)As;           // 128 floats
    float* Lb2 = Lb1 + 128;
    int*   Li  = (int*)(Lb2 + 128);
    if (wc == 1 && m == 0) {
        #pragma unroll
        for (int ri = 0; ri < 16; ++ri) {
            int row = wr * 64 + (ri >> 2) * 16 + quad * 4 + (ri & 3);
            Lb1[row] = b1[ri]; Lb2[row] = b2[ri]; Li[row] = i1[ri];
        }
    }
    __syncthreads();
    if (wc == 0 && m == 0) {
        #pragma unroll
        for (int ri = 0; ri < 16; ++ri) {
            int row = wr * 64 + (ri >> 2) * 16 + quad * 4 + (ri & 3);
            float o1 = Lb1[row], o2 = Lb2[row]; int oi = Li[row];
            if (o1 < b1[ri] || (o1 == b1[ri] && oi < i1[ri])) {
                b2[ri] = fminf(b1[ri], o2); b1[ri] = o1; i1[ri] = oi;
            } else {
                b2[ri] = fminf(b2[ri], o1);
            }
            const int tok = tok0 + row;
            pb1[nt_i * NTOT + tok] = b1[ri];
            pb2[nt_i * NTOT + tok] = b2[ri];
            pi [nt_i * NTOT + tok] = i1[ri];
        }
    }
}

// ---------- merge per-code-tile partials (ascending tile order) ----------
__global__ __launch_bounds__(256) void fmerge_kernel(
    const float* __restrict__ pb1, const float* __restrict__ pb2,
    const int* __restrict__ pi, float* __restrict__ out_idx_f,
    float* __restrict__ score, int* __restrict__ cnt, int* __restrict__ list)
{
    const int tok = blockIdx.x * 256 + threadIdx.x;
    float b1 = 3.4e38f, b2 = 3.4e38f; int i1 = 0;
    #pragma unroll
    for (int j = 0; j < 8; ++j) {
        float o1 = pb1[j * NTOT + tok];
        float o2 = pb2[j * NTOT + tok];
        int   oi = pi [j * NTOT + tok];
        if (o1 < b1 || (o1 == b1 && oi < i1)) {
            b2 = fminf(b1, o2); b1 = o1; i1 = oi;
        } else {
            b2 = fminf(b2, o1);
        }
    }
    out_idx_f[tok] = (float)i1;
    score[tok] = b1;                   // w2[k*] - 2*dot  (loss term)
    if (b2 - b1 <= TAU) {
        int p = atomicAdd(cnt, 1);
        list[p] = tok;
    }
}

// ---------- exact np-emulating recheck, 4 rows per block ----------
// Coalesced: thread owns 4 CONSECUTIVE codes (k0=tid*4) read from transposed
// codebook cbT[d][k]; f64 accumulation order per (row,code) chain is identical
// (d-ascending) to the round-3-validated kernel -> bitwise-same results.
// (indices only; score left stale — contributes < 1e-7 to the loss)
__global__ __launch_bounds__(256) void recheck_kernel(
    const float* __restrict__ z, const float* __restrict__ cbT,
    const float* __restrict__ w2, const int* __restrict__ cnt,
    const int* __restrict__ list, float* __restrict__ out_idx_f)
{
    __shared__ float zrow[4][DIMD];
    __shared__ float z2s[4];
    __shared__ float rv[4][4];
    __shared__ int   ri[4][4];

    const int tid  = threadIdx.x;
    const int wave = tid >> 6;
    const int lane = tid & 63;
    const int total = *cnt;
    const int ngrp = (total + 3) >> 2;
    const int k0 = tid * 4;

    for (int g = blockIdx.x; g < ngrp; g += gridDim.x) {
        __syncthreads();
        const int nrows = min(4, total - g * 4);
        {
            int idx = g * 4 + wave;
            int tok = (idx < total) ? list[idx] : list[g * 4];
            int b = tok >> 11, t = tok & 2047;
            const float* zb = z + (size_t)b * DIMD * TT + t;
            double zp = 0.0;
            #pragma unroll
            for (int j = 0; j < 8; ++j) {
                int d = lane + 64 * j;
                float v = zb[(size_t)d * TT];
                zrow[wave][d] = v;
                float vv = v * v;
                zp += (double)vv;
            }
            #pragma unroll
            for (int msk = 1; msk < 64; msk <<= 1) zp += __shfl_xor(zp, msk, 64);
            if (lane == 0) z2s[wave] = (float)zp;
        }
        __syncthreads();

        double acc[4][4] = {};   // [row][code]
        // prefetch double-buffer over d
        f32x4 cw0 = *(const f32x4*)(cbT + (size_t)0 * KCB + k0);
        f32x4 cw1 = *(const f32x4*)(cbT + (size_t)1 * KCB + k0);
        f32x4 cw2 = *(const f32x4*)(cbT + (size_t)2 * KCB + k0);
        f32x4 cw3 = *(const f32x4*)(cbT + (size_t)3 * KCB + k0);
        for (int d = 0; d < DIMD; d += 4) {
            f32x4 n0, n1, n2, n3;
            if (d + 4 < DIMD) {
                n0 = *(const f32x4*)(cbT + (size_t)(d + 4) * KCB + k0);
                n1 = *(const f32x4*)(cbT + (size_t)(d + 5) * KCB + k0);
                n2 = *(const f32x4*)(cbT + (size_t)(d + 6) * KCB + k0);
                n3 = *(const f32x4*)(cbT + (size_t)(d + 7) * KCB + k0);
            }
            #pragma unroll
            for (int r = 0; r < 4; ++r) {
                f32x4 zv = *(const f32x4*)&zrow[r][d];
                #pragma unroll
                for (int j = 0; j < 4; ++j) {
                    acc[r][j] = fma((double)zv[0], (double)cw0[j], acc[r][j]);
                    acc[r][j] = fma((double)zv[1], (double)cw1[j], acc[r][j]);
                    acc[r][j] = fma((double)zv[2], (double)cw2[j], acc[r][j]);
                    acc[r][j] = fma((double)zv[3], (double)cw3[j], acc[r][j]);
                }
            }
            cw0 = n0; cw1 = n1; cw2 = n2; cw3 = n3;
        }

        f32x4 w2q = *(const f32x4*)(w2 + k0);
        float bv[4]; int bi[4];
        #pragma unroll
        for (int r = 0; r < 4; ++r) { bv[r] = 3.4e38f; bi[r] = 0; }
        #pragma unroll
        for (int r = 0; r < 4; ++r)
            #pragma unroll
            for (int j = 0; j < 4; ++j) {
                float dotf = (float)acc[r][j];
                float t2   = z2s[r] - 2.0f * dotf;
                float s    = t2 + w2q[j];
                // j ascending => ties keep smaller k automatically
                if (s < bv[r]) { bv[r] = s; bi[r] = k0 + j; }
            }
        #pragma unroll
        for (int msk = 1; msk < 64; msk <<= 1) {
            #pragma unroll
            for (int r = 0; r < 4; ++r) {
                float ov = __shfl_xor(bv[r], msk, 64);
                int   oi = __shfl_xor(bi[r], msk, 64);
                if (ov < bv[r] || (ov == bv[r] && oi < bi[r])) { bv[r] = ov; bi[r] = oi; }
            }
        }
        if (lane == 0) {
            #pragma unroll
            for (int r = 0; r < 4; ++r) { rv[wave][r] = bv[r]; ri[wave][r] = bi[r]; }
        }
        __syncthreads();
        if (tid < nrows) {
            float v = rv[0][tid]; int k = ri[0][tid];
            #pragma unroll
            for (int w = 1; w < 4; ++w) {
                if (rv[w][tid] < v || (rv[w][tid] == v && ri[w][tid] < k)) {
                    v = rv[w][tid]; k = ri[w][tid];
                }
            }
            out_idx_f[list[g * 4 + tid]] = (float)k;
        }
    }
}

// ---------- pure gather: out = codebook[idx]  (z_q_st forward value == z_q) ----------
__global__ __launch_bounds__(256) void gather_kernel(
    const float* __restrict__ cb, const float* __restrict__ idx_f,
    float* __restrict__ out)
{
    const size_t base = ((size_t)blockIdx.x * 256 + threadIdx.x) * 4;
    const int t  = (int)(base % TT);
    const int bd = (int)(base / TT);
    const int d  = bd & (DIMD - 1);
    const int b  = bd >> 9;

    const float* ip = idx_f + b * TT + t;
    int k0 = (int)(ip[0] + 0.5f);
    int k1 = (int)(ip[1] + 0.5f);
    int k2 = (int)(ip[2] + 0.5f);
    int k3 = (int)(ip[3] + 0.5f);
    float4 ov = make_float4(cb[(size_t)k0 * DIMD + d],
                            cb[(size_t)k1 * DIMD + d],
                            cb[(size_t)k2 * DIMD + d],
                            cb[(size_t)k3 * DIMD + d]);
    *(float4*)(out + base) = ov;
}

// ---------- loss = 1.25/(N*D) * sum_n (z2[n] + score[n]) ----------
__global__ __launch_bounds__(256) void loss_kernel(const float* __restrict__ z2,
                                                   const float* __restrict__ score,
                                                   float* __restrict__ loss)
{
    __shared__ double red[4];
    const int idx = blockIdx.x * 1024 + threadIdx.x * 4;   // grid 32
    float4 a = *(const float4*)(z2 + idx);
    float4 s = *(const float4*)(score + idx);
    double part = ((double)a.x + (double)s.x) + ((double)a.y + (double)s.y) +
                  ((double)a.z + (double)s.z) + ((double)a.w + (double)s.w);
    #pragma unroll
    for (int m = 1; m < 64; m <<= 1) part += __shfl_xor(part, m, 64);
    const int lane = threadIdx.x & 63, wv = threadIdx.x >> 6;
    if (lane == 0) red[wv] = part;
    __syncthreads();
    if (threadIdx.x == 0) {
        double tot = red[0] + red[1] + red[2] + red[3];
        atomicAdd(loss, (float)(tot * (1.25 / (double)(BB * DIMD * TT))));
    }
}

extern "C" void kernel_launch(void* const* d_in, const int* in_sizes, int n_in,
                              void* d_out, int out_size, void* d_ws, size_t ws_size,
                              hipStream_t stream) {
    const float* z  = (const float*)d_in[0];
    const float* cb = (const float*)d_in[1];
    float* out = (float*)d_out;

    // Scratch parked inside the 64MB z_q_st output region (all consumed
    // before gather_kernel overwrites it):
    //   zf  @ 0MB   (32MB fp16 token-major z)
    //   cbT @ 33MB  (2MB fp32 transposed codebook)
    //   pb1 @ 36MB, pb2 @ 37MB, pi @ 38MB  (1MB each: 8 x 32768 partials)
    f16_t* zf  = (f16_t*)out;
    float* cbT = (float*)((char*)out + (33u << 20));
    float* pb1 = (float*)((char*)out + (36u << 20));
    float* pb2 = (float*)((char*)out + (37u << 20));
    int*   pi  = (int*)  ((char*)out + (38u << 20));

    char* wsb = (char*)d_ws;
    f16_t* wf    = (f16_t*)wsb;                         // 1 MB
    float* w2    = (float*)(wsb + (1 << 20));           // 4 KB
    int*   cnt   = (int*)(wsb + (1 << 20) + 4096);
    int*   list  = (int*)(wsb + (1 << 20) + 8192);      // 128 KB
    float* z2    = (float*)(wsb + (1 << 20) + 8192 + (128 << 10));   // 128 KB
    float* score = z2 + NTOT;                           // 128 KB

    hipMemsetAsync(out + OUT_LOSS, 0, sizeof(float), stream);
    hipMemsetAsync(cnt, 0, sizeof(int), stream);
    prep_kernel<<<KCB / 4, 256, 0, stream>>>(cb, wf, w2, cbT);
    tsplit_kernel<<<NTOT / 64, 256, 0, stream>>>(z, zf, z2);
    fast_kernel<<<(NTOT / 128) * 8, 256, 0, stream>>>(zf, wf, w2, pb1, pb2, pi);
    fmerge_kernel<<<NTOT / 256, 256, 0, stream>>>(
        pb1, pb2, pi, out + OUT_IDX, score, cnt, list);
    recheck_kernel<<<512, 256, 0, stream>>>(z, cbT, w2, cnt, list, out + OUT_IDX);
    gather_kernel<<<(BB * DIMD * TT) / (256 * 4), 256, 0, stream>>>(
        cb, out + OUT_IDX, out);
    loss_kernel<<<NTOT / 1024, 256, 0, stream>>>(z2, score, out + OUT_LOSS);
}

// Round 10
// 321.850 us; speedup vs baseline: 1.2097x; 1.2097x over previous
//
#include <hip/hip_runtime.h>

typedef _Float16 f16_t;
typedef _Float16 f16x8 __attribute__((ext_vector_type(8)));
typedef float    f32x4 __attribute__((ext_vector_type(4)));

#define DIMD 512
#define KCB  1024
#define TT   2048
#define BB   16
#define NTOT (BB*TT)                   // 32768
#define OUT_IDX  (BB*DIMD*TT)          // 16777216
#define OUT_LOSS (OUT_IDX + NTOT)
#define TAU 3.0e-4f
// score = w2[k] - 2*dot; fast dot computed on (z, 1024*w) -> scale back by 2^-10
#define NEG2_SCALE (-0.001953125f)     // -2/1024, exact
#define BTOK 64                        // tokens per fast_kernel block

__device__ __forceinline__ void gll16(const f16_t* g, f16_t* l) {
    __builtin_amdgcn_global_load_lds(
        (const __attribute__((address_space(1))) unsigned int*)g,
        (__attribute__((address_space(3))) unsigned int*)l, 16, 0, 0);
}

// ---------- prep: wf16[k][d] = f16(1024*cb), w2[k] = fl32(fp64 sum fl32(cb^2)),
// ----------       cbT[d][k] = cb[k][d]  (fp32 transposed codebook for recheck) ----------
__global__ __launch_bounds__(256) void prep_kernel(const float* __restrict__ cb,
                                                   f16_t* __restrict__ wf,
                                                   float* __restrict__ w2,
                                                   float* __restrict__ cbT) {
    const int wave = threadIdx.x >> 6, lane = threadIdx.x & 63;
    const int row  = blockIdx.x * 4 + wave;
    const float* src = cb + (size_t)row * DIMD + lane * 8;
    float4 v0 = *(const float4*)(src);
    float4 v1 = *(const float4*)(src + 4);
    f16x8 o;
    o[0] = (f16_t)(v0.x * 1024.f); o[1] = (f16_t)(v0.y * 1024.f);
    o[2] = (f16_t)(v0.z * 1024.f); o[3] = (f16_t)(v0.w * 1024.f);
    o[4] = (f16_t)(v1.x * 1024.f); o[5] = (f16_t)(v1.y * 1024.f);
    o[6] = (f16_t)(v1.z * 1024.f); o[7] = (f16_t)(v1.w * 1024.f);
    *(f16x8*)(wf + (size_t)row * DIMD + lane * 8) = o;
    // transposed fp32 copy (scattered 4B stores; 2MB total, negligible)
    float vals[8] = {v0.x, v0.y, v0.z, v0.w, v1.x, v1.y, v1.z, v1.w};
    #pragma unroll
    for (int u = 0; u < 8; ++u)
        cbT[(size_t)(lane * 8 + u) * KCB + row] = vals[u];
    float s0 = v0.x * v0.x, s1 = v0.y * v0.y, s2 = v0.z * v0.z, s3 = v0.w * v0.w;
    float s4 = v1.x * v1.x, s5 = v1.y * v1.y, s6 = v1.z * v1.z, s7 = v1.w * v1.w;
    double s = (double)s0 + (double)s1 + (double)s2 + (double)s3 +
               (double)s4 + (double)s5 + (double)s6 + (double)s7;
    #pragma unroll
    for (int m = 1; m < 64; m <<= 1) s += __shfl_xor(s, m, 64);
    if (lane == 0) w2[row] = (float)s;
}

// ---------- fast argmin, tsplit FUSED: A staged straight from f32 z
// ----------  (strided loads + f16 convert + swizzled ds_write, z2 computed
// ----------  in-pass exactly as tsplit did), B via gll16 double-buffer,
// ----------  R8 loop structure. 64 tok x 1024 codes, 256 thr, 80KB LDS,
// ----------  2 blocks/CU.
__global__ __launch_bounds__(256, 2) void fast_kernel(
    const float* __restrict__ z, const f16_t* __restrict__ wf,
    const float* __restrict__ w2, float* __restrict__ out_idx_f,
    float* __restrict__ score, float* __restrict__ z2,
    int* __restrict__ cnt, int* __restrict__ list)
{
    extern __shared__ __align__(16) char smem[];
    f16_t* As = (f16_t*)smem;                     // 64 tok x 512 d = 64KB swizzled
    f16_t* Bs = (f16_t*)(smem + (64 << 10));      // 2 x 8KB (128 codes x 32 d)

    const int tid  = threadIdx.x;      // 0..255
    const int wave = tid >> 6;         // 0..3
    const int lane = tid & 63;
    const int m    = lane & 15;
    const int quad = lane >> 4;
    const int rh   = wave & 1;         // token half (32 tok)
    const int chh  = wave >> 1;        // code half (64 of each 128-tile)
    const int tok0 = blockIdx.x * BTOK;

    // ---- A phase (= old tsplit, bitwise-identical values & zp order):
    // lane = token, wave covers d in [wave*128, wave*128+128).
    // Global group gd stored at LDS slot gd^(row&7) -> same As content as the
    // R8 gll16(pre-swizzled-source) path.
    double zp;
    {
        const int tok = tok0 + lane;
        const int b = tok >> 11, t = tok & 2047;
        const float* src = z + (size_t)b * DIMD * TT + t;
        const int d0 = wave * 128;
        zp = 0.0;
        f16_t* arow = As + lane * DIMD;
        const int x7 = lane & 7;
        for (int j = 0; j < 16; ++j) {
            f16x8 o;
            #pragma unroll
            for (int u = 0; u < 8; ++u) {
                float v = src[(size_t)(d0 + j * 8 + u) * TT];
                o[u] = (f16_t)v;
                float vv = v * v;
                zp += (double)vv;
            }
            *(f16x8*)(arow + (((wave * 16 + j) ^ x7) * 8)) = o;
        }
    }
    // zred handoff in Bs buf1 (overwritten only after the 2nd barrier below)
    float* zredp = (float*)(Bs + 4096);           // 4 x 64 floats
    zredp[wave * 64 + lane] = (float)zp;

    // ---- B staging bases: chunk = 128 codes x 32 d = 8KB, 2 gll16/thread ----
    // slot s: row = s>>2 (0..127), p = s&3; source group swizzle p ^ ((row>>1)&3)
    const f16_t* gB[2]; f16_t* lB[2];
    #pragma unroll
    for (int q = 0; q < 2; ++q) {
        int s = q * 256 + tid;
        int row = s >> 2, p = s & 3;
        gB[q] = wf + (size_t)row * DIMD + (p ^ ((row >> 1) & 3)) * 8;
        lB[q] = Bs + s * 8;                    // + buf*4096 (f16 units)
    }
    // prologue: stage chunk 0 into buf 0
    gll16(gB[0], lB[0]);
    gll16(gB[1], lB[1]);
    __syncthreads();                            // A writes + zred + chunk0

    // z2 = fl32 sum of the 4 wave partials, left-to-right (== tsplit)
    if (wave == 0)
        z2[tok0 + lane] = ((zredp[lane] + zredp[64 + lane]) + zredp[128 + lane])
                          + zredp[192 + lane];
    __syncthreads();                            // protect buf1 until read done

    float b1[8], b2[8]; int i1[8];
    #pragma unroll
    for (int r = 0; r < 8; ++r) { b1[r] = 3.4e38f; b2[r] = 3.4e38f; i1[r] = 0; }

    // read-side constants
    const int a7 = m & 7;
    const f16_t* Arow0 = As + (rh * 32 + m) * DIMD;   // + mt*16*DIMD
    const int bq = (quad ^ ((m >> 1) & 3)) * 8;       // B read group, all nt
    const int br = chh * 64 + m;                      // + nt*16; row stride 32 f16

    for (int ct = 0; ct < 8; ++ct) {
        f32x4 acc[2][4] = {};
        #pragma unroll
        for (int dcc = 0; dcc < 16; ++dcc) {
            const int n = ct * 16 + dcc;
            // phase 1: issue next chunk's staging into the other buffer
            if (n + 1 < 128) {
                const int nct = (n + 1) >> 4, ndc = (n + 1) & 15;
                const size_t off = (size_t)nct * (128 * DIMD) + (size_t)ndc * 32;
                const int wb = (n + 1) & 1;
                gll16(gB[0] + off, lB[0] + wb * 4096);
                gll16(gB[1] + off, lB[1] + wb * 4096);
            }
            // phase 2: compute current chunk (K = dcc*32 .. +32, ascending)
            {
                const f16_t* Bc = Bs + (n & 1) * 4096;
                const int aswz = ((dcc * 4 + quad) ^ a7) * 8;
                f16x8 af0 = *(const f16x8*)(Arow0 + aswz);
                f16x8 af1 = *(const f16x8*)(Arow0 + 16 * DIMD + aswz);
                f16x8 bf0 = *(const f16x8*)(Bc + (br +  0) * 32 + bq);
                f16x8 bf1 = *(const f16x8*)(Bc + (br + 16) * 32 + bq);
                f16x8 bf2 = *(const f16x8*)(Bc + (br + 32) * 32 + bq);
                f16x8 bf3 = *(const f16x8*)(Bc + (br + 48) * 32 + bq);
                __builtin_amdgcn_s_setprio(1);
                acc[0][0] = __builtin_amdgcn_mfma_f32_16x16x32_f16(af0, bf0, acc[0][0], 0, 0, 0);
                acc[0][1] = __builtin_amdgcn_mfma_f32_16x16x32_f16(af0, bf1, acc[0][1], 0, 0, 0);
                acc[0][2] = __builtin_amdgcn_mfma_f32_16x16x32_f16(af0, bf2, acc[0][2], 0, 0, 0);
                acc[0][3] = __builtin_amdgcn_mfma_f32_16x16x32_f16(af0, bf3, acc[0][3], 0, 0, 0);
                acc[1][0] = __builtin_amdgcn_mfma_f32_16x16x32_f16(af1, bf0, acc[1][0], 0, 0, 0);
                acc[1][1] = __builtin_amdgcn_mfma_f32_16x16x32_f16(af1, bf1, acc[1][1], 0, 0, 0);
                acc[1][2] = __builtin_amdgcn_mfma_f32_16x16x32_f16(af1, bf2, acc[1][2], 0, 0, 0);
                acc[1][3] = __builtin_amdgcn_mfma_f32_16x16x32_f16(af1, bf3, acc[1][3], 0, 0, 0);
                __builtin_amdgcn_s_setprio(0);
            }
            __syncthreads();   // drains staging + releases consumed buffer
        }
        // ---- ct epilogue: tracker update (w2 from global, L2-hot 4KB) ----
        #pragma unroll
        for (int nt = 0; nt < 4; ++nt) {
            const int col = ct * 128 + chh * 64 + nt * 16 + m;
            const float w2c = w2[col];
            #pragma unroll
            for (int mt = 0; mt < 2; ++mt)
                #pragma unroll
                for (int r = 0; r < 4; ++r) {
                    float s = fmaf(NEG2_SCALE, acc[mt][nt][r], w2c);
                    const int ri = mt * 4 + r;
                    if (s < b1[ri]) { b2[ri] = b1[ri]; b1[ri] = s; i1[ri] = col; }
                    else if (s < b2[ri]) b2[ri] = s;
                }
        }
    }

    // reduce over the 16 m-lanes (code dimension within fragment)
    #pragma unroll
    for (int msk = 1; msk < 16; msk <<= 1) {
        #pragma unroll
        for (int ri = 0; ri < 8; ++ri) {
            float o1 = __shfl_xor(b1[ri], msk, 64);
            int   oi = __shfl_xor(i1[ri], msk, 64);
            float o2 = __shfl_xor(b2[ri], msk, 64);
            if (o1 < b1[ri] || (o1 == b1[ri] && oi < i1[ri])) {
                b2[ri] = fminf(b1[ri], o2); b1[ri] = o1; i1[ri] = oi;
            } else {
                b2[ri] = fminf(b2[ri], o1);
            }
        }
    }

    // merge the two code-halves (chh) via LDS scratch reusing As
    // (loop ended with __syncthreads -> all As reads complete)
    float* Lb1 = (float*)As;           // 64 floats
    float* Lb2 = Lb1 + 64;
    int*   Li  = (int*)(Lb2 + 64);
    if (chh == 1 && m == 0) {
        #pragma unroll
        for (int ri = 0; ri < 8; ++ri) {
            int row = rh * 32 + (ri >> 2) * 16 + quad * 4 + (ri & 3);
            Lb1[row] = b1[ri]; Lb2[row] = b2[ri]; Li[row] = i1[ri];
        }
    }
    __syncthreads();
    if (chh == 0 && m == 0) {
        #pragma unroll
        for (int ri = 0; ri < 8; ++ri) {
            int row = rh * 32 + (ri >> 2) * 16 + quad * 4 + (ri & 3);
            float o1 = Lb1[row], o2 = Lb2[row]; int oi = Li[row];
            if (o1 < b1[ri] || (o1 == b1[ri] && oi < i1[ri])) {
                b2[ri] = fminf(b1[ri], o2); b1[ri] = o1; i1[ri] = oi;
            } else {
                b2[ri] = fminf(b2[ri], o1);
            }
            int tok = tok0 + row;
            out_idx_f[tok] = (float)i1[ri];
            score[tok] = b1[ri];           // w2[k*] - 2*dot  (loss term)
            if (b2[ri] - b1[ri] <= TAU) {
                int p = atomicAdd(cnt, 1);
                list[p] = tok;
            }
        }
    }
}

// ---------- exact np-emulating recheck, 4 rows per block ----------
// Coalesced: thread owns 4 CONSECUTIVE codes (k0=tid*4) read from transposed
// codebook cbT[d][k]; f64 accumulation order per (row,code) chain is identical
// (d-ascending) to the round-3-validated kernel -> bitwise-same results.
// (indices only; score left stale — contributes < 1e-7 to the loss)
__global__ __launch_bounds__(256) void recheck_kernel(
    const float* __restrict__ z, const float* __restrict__ cbT,
    const float* __restrict__ w2, const int* __restrict__ cnt,
    const int* __restrict__ list, float* __restrict__ out_idx_f)
{
    __shared__ float zrow[4][DIMD];
    __shared__ float z2s[4];
    __shared__ float rv[4][4];
    __shared__ int   ri[4][4];

    const int tid  = threadIdx.x;
    const int wave = tid >> 6;
    const int lane = tid & 63;
    const int total = *cnt;
    const int ngrp = (total + 3) >> 2;
    const int k0 = tid * 4;

    for (int g = blockIdx.x; g < ngrp; g += gridDim.x) {
        __syncthreads();
        const int nrows = min(4, total - g * 4);
        {
            int idx = g * 4 + wave;
            int tok = (idx < total) ? list[idx] : list[g * 4];
            int b = tok >> 11, t = tok & 2047;
            const float* zb = z + (size_t)b * DIMD * TT + t;
            double zp = 0.0;
            #pragma unroll
            for (int j = 0; j < 8; ++j) {
                int d = lane + 64 * j;
                float v = zb[(size_t)d * TT];
                zrow[wave][d] = v;
                float vv = v * v;
                zp += (double)vv;
            }
            #pragma unroll
            for (int msk = 1; msk < 64; msk <<= 1) zp += __shfl_xor(zp, msk, 64);
            if (lane == 0) z2s[wave] = (float)zp;
        }
        __syncthreads();

        double acc[4][4] = {};   // [row][code]
        // prefetch double-buffer over d
        f32x4 cw0 = *(const f32x4*)(cbT + (size_t)0 * KCB + k0);
        f32x4 cw1 = *(const f32x4*)(cbT + (size_t)1 * KCB + k0);
        f32x4 cw2 = *(const f32x4*)(cbT + (size_t)2 * KCB + k0);
        f32x4 cw3 = *(const f32x4*)(cbT + (size_t)3 * KCB + k0);
        for (int d = 0; d < DIMD; d += 4) {
            f32x4 n0, n1, n2, n3;
            if (d + 4 < DIMD) {
                n0 = *(const f32x4*)(cbT + (size_t)(d + 4) * KCB + k0);
                n1 = *(const f32x4*)(cbT + (size_t)(d + 5) * KCB + k0);
                n2 = *(const f32x4*)(cbT + (size_t)(d + 6) * KCB + k0);
                n3 = *(const f32x4*)(cbT + (size_t)(d + 7) * KCB + k0);
            }
            #pragma unroll
            for (int r = 0; r < 4; ++r) {
                f32x4 zv = *(const f32x4*)&zrow[r][d];
                #pragma unroll
                for (int j = 0; j < 4; ++j) {
                    acc[r][j] = fma((double)zv[0], (double)cw0[j], acc[r][j]);
                    acc[r][j] = fma((double)zv[1], (double)cw1[j], acc[r][j]);
                    acc[r][j] = fma((double)zv[2], (double)cw2[j], acc[r][j]);
                    acc[r][j] = fma((double)zv[3], (double)cw3[j], acc[r][j]);
                }
            }
            cw0 = n0; cw1 = n1; cw2 = n2; cw3 = n3;
        }

        f32x4 w2q = *(const f32x4*)(w2 + k0);
        float bv[4]; int bi[4];
        #pragma unroll
        for (int r = 0; r < 4; ++r) { bv[r] = 3.4e38f; bi[r] = 0; }
        #pragma unroll
        for (int r = 0; r < 4; ++r)
            #pragma unroll
            for (int j = 0; j < 4; ++j) {
                float dotf = (float)acc[r][j];
                float t2   = z2s[r] - 2.0f * dotf;
                float s    = t2 + w2q[j];
                // j ascending => ties keep smaller k automatically
                if (s < bv[r]) { bv[r] = s; bi[r] = k0 + j; }
            }
        #pragma unroll
        for (int msk = 1; msk < 64; msk <<= 1) {
            #pragma unroll
            for (int r = 0; r < 4; ++r) {
                float ov = __shfl_xor(bv[r], msk, 64);
                int   oi = __shfl_xor(bi[r], msk, 64);
                if (ov < bv[r] || (ov == bv[r] && oi < bi[r])) { bv[r] = ov; bi[r] = oi; }
            }
        }
        if (lane == 0) {
            #pragma unroll
            for (int r = 0; r < 4; ++r) { rv[wave][r] = bv[r]; ri[wave][r] = bi[r]; }
        }
        __syncthreads();
        if (tid < nrows) {
            float v = rv[0][tid]; int k = ri[0][tid];
            #pragma unroll
            for (int w = 1; w < 4; ++w) {
                if (rv[w][tid] < v || (rv[w][tid] == v && ri[w][tid] < k)) {
                    v = rv[w][tid]; k = ri[w][tid];
                }
            }
            out_idx_f[list[g * 4 + tid]] = (float)k;
        }
    }
}

// ---------- pure gather: out = codebook[idx]  (z_q_st forward value == z_q) ----------
__global__ __launch_bounds__(256) void gather_kernel(
    const float* __restrict__ cb, const float* __restrict__ idx_f,
    float* __restrict__ out)
{
    const size_t base = ((size_t)blockIdx.x * 256 + threadIdx.x) * 4;
    const int t  = (int)(base % TT);
    const int bd = (int)(base / TT);
    const int d  = bd & (DIMD - 1);
    const int b  = bd >> 9;

    const float* ip = idx_f + b * TT + t;
    int k0 = (int)(ip[0] + 0.5f);
    int k1 = (int)(ip[1] + 0.5f);
    int k2 = (int)(ip[2] + 0.5f);
    int k3 = (int)(ip[3] + 0.5f);
    float4 ov = make_float4(cb[(size_t)k0 * DIMD + d],
                            cb[(size_t)k1 * DIMD + d],
                            cb[(size_t)k2 * DIMD + d],
                            cb[(size_t)k3 * DIMD + d]);
    *(float4*)(out + base) = ov;
}

// ---------- loss = 1.25/(N*D) * sum_n (z2[n] + score[n]) ----------
__global__ __launch_bounds__(256) void loss_kernel(const float* __restrict__ z2,
                                                   const float* __restrict__ score,
                                                   float* __restrict__ loss)
{
    __shared__ double red[4];
    const int idx = blockIdx.x * 1024 + threadIdx.x * 4;   // grid 32
    float4 a = *(const float4*)(z2 + idx);
    float4 s = *(const float4*)(score + idx);
    double part = ((double)a.x + (double)s.x) + ((double)a.y + (double)s.y) +
                  ((double)a.z + (double)s.z) + ((double)a.w + (double)s.w);
    #pragma unroll
    for (int m = 1; m < 64; m <<= 1) part += __shfl_xor(part, m, 64);
    const int lane = threadIdx.x & 63, wv = threadIdx.x >> 6;
    if (lane == 0) red[wv] = part;
    __syncthreads();
    if (threadIdx.x == 0) {
        double tot = red[0] + red[1] + red[2] + red[3];
        atomicAdd(loss, (float)(tot * (1.25 / (double)(BB * DIMD * TT))));
    }
}

extern "C" void kernel_launch(void* const* d_in, const int* in_sizes, int n_in,
                              void* d_out, int out_size, void* d_ws, size_t ws_size,
                              hipStream_t stream) {
    const float* z  = (const float*)d_in[0];
    const float* cb = (const float*)d_in[1];
    float* out = (float*)d_out;

    // cbT (2MB fp32 transposed codebook) parked inside the z_q_st output
    // region at +33MB; consumed by recheck before gather overwrites out.
    float* cbT = (float*)((char*)out + (33u << 20));

    char* wsb = (char*)d_ws;
    f16_t* wf    = (f16_t*)wsb;                         // 1 MB
    float* w2    = (float*)(wsb + (1 << 20));           // 4 KB
    int*   cnt   = (int*)(wsb + (1 << 20) + 4096);
    int*   list  = (int*)(wsb + (1 << 20) + 8192);      // 128 KB
    float* z2    = (float*)(wsb + (1 << 20) + 8192 + (128 << 10));   // 128 KB
    float* score = z2 + NTOT;                           // 128 KB

    hipMemsetAsync(out + OUT_LOSS, 0, sizeof(float), stream);
    hipMemsetAsync(cnt, 0, sizeof(int), stream);
    prep_kernel<<<KCB / 4, 256, 0, stream>>>(cb, wf, w2, cbT);
    fast_kernel<<<NTOT / BTOK, 256, 80 << 10, stream>>>(
        z, wf, w2, out + OUT_IDX, score, z2, cnt, list);
    recheck_kernel<<<512, 256, 0, stream>>>(z, cbT, w2, cnt, list, out + OUT_IDX);
    gather_kernel<<<(BB * DIMD * TT) / (256 * 4), 256, 0, stream>>>(
        cb, out + OUT_IDX, out);
    loss_kernel<<<NTOT / 1024, 256, 0, stream>>>(z2, score, out + OUT_LOSS);
}

// Round 11
// 280.680 us; speedup vs baseline: 1.3872x; 1.1467x over previous
//
#include <hip/hip_runtime.h>

typedef _Float16 f16_t;
typedef _Float16 f16x8 __attribute__((ext_vector_type(8)));
typedef float    f32x4 __attribute__((ext_vector_type(4)));
typedef float    f32x2 __attribute__((ext_vector_type(2)));

#define DIMD 512
#define KCB  1024
#define TT   2048
#define BB   16
#define NTOT (BB*TT)                   // 32768
#define OUT_IDX  (BB*DIMD*TT)          // 16777216
#define OUT_LOSS (OUT_IDX + NTOT)
#define TAU 3.0e-4f
// score = w2[k] - 2*dot; fast dot computed on (z, 1024*w) -> scale back by 2^-10
#define NEG2_SCALE (-0.001953125f)     // -2/1024, exact
#define BTOK 64                        // tokens per fast_kernel block

__device__ __forceinline__ void gll16(const f16_t* g, f16_t* l) {
    __builtin_amdgcn_global_load_lds(
        (const __attribute__((address_space(1))) unsigned int*)g,
        (__attribute__((address_space(3))) unsigned int*)l, 16, 0, 0);
}

// ---------- prep: wf16[k][d] = f16(1024*cb), w2[k] = fl32(fp64 sum fl32(cb^2)),
// ----------       cbT[d][k] = cb[k][d]  (fp32 transposed codebook for recheck) ----------
__global__ __launch_bounds__(256) void prep_kernel(const float* __restrict__ cb,
                                                   f16_t* __restrict__ wf,
                                                   float* __restrict__ w2,
                                                   float* __restrict__ cbT) {
    const int wave = threadIdx.x >> 6, lane = threadIdx.x & 63;
    const int row  = blockIdx.x * 4 + wave;
    const float* src = cb + (size_t)row * DIMD + lane * 8;
    float4 v0 = *(const float4*)(src);
    float4 v1 = *(const float4*)(src + 4);
    f16x8 o;
    o[0] = (f16_t)(v0.x * 1024.f); o[1] = (f16_t)(v0.y * 1024.f);
    o[2] = (f16_t)(v0.z * 1024.f); o[3] = (f16_t)(v0.w * 1024.f);
    o[4] = (f16_t)(v1.x * 1024.f); o[5] = (f16_t)(v1.y * 1024.f);
    o[6] = (f16_t)(v1.z * 1024.f); o[7] = (f16_t)(v1.w * 1024.f);
    *(f16x8*)(wf + (size_t)row * DIMD + lane * 8) = o;
    // transposed fp32 copy (scattered 4B stores; 2MB total, negligible)
    float vals[8] = {v0.x, v0.y, v0.z, v0.w, v1.x, v1.y, v1.z, v1.w};
    #pragma unroll
    for (int u = 0; u < 8; ++u)
        cbT[(size_t)(lane * 8 + u) * KCB + row] = vals[u];
    float s0 = v0.x * v0.x, s1 = v0.y * v0.y, s2 = v0.z * v0.z, s3 = v0.w * v0.w;
    float s4 = v1.x * v1.x, s5 = v1.y * v1.y, s6 = v1.z * v1.z, s7 = v1.w * v1.w;
    double s = (double)s0 + (double)s1 + (double)s2 + (double)s3 +
               (double)s4 + (double)s5 + (double)s6 + (double)s7;
    #pragma unroll
    for (int m = 1; m < 64; m <<= 1) s += __shfl_xor(s, m, 64);
    if (lane == 0) w2[row] = (float)s;
}

// ---------- fast argmin, tsplit FUSED (validated round 10, ~96us) ----------
__global__ __launch_bounds__(256, 2) void fast_kernel(
    const float* __restrict__ z, const f16_t* __restrict__ wf,
    const float* __restrict__ w2, float* __restrict__ out_idx_f,
    float* __restrict__ score, float* __restrict__ z2,
    int* __restrict__ cnt, int* __restrict__ list)
{
    extern __shared__ __align__(16) char smem[];
    f16_t* As = (f16_t*)smem;                     // 64 tok x 512 d = 64KB swizzled
    f16_t* Bs = (f16_t*)(smem + (64 << 10));      // 2 x 8KB (128 codes x 32 d)

    const int tid  = threadIdx.x;      // 0..255
    const int wave = tid >> 6;         // 0..3
    const int lane = tid & 63;
    const int m    = lane & 15;
    const int quad = lane >> 4;
    const int rh   = wave & 1;         // token half (32 tok)
    const int chh  = wave >> 1;        // code half (64 of each 128-tile)
    const int tok0 = blockIdx.x * BTOK;

    // ---- A phase (= old tsplit, bitwise-identical values & zp order) ----
    double zp;
    {
        const int tok = tok0 + lane;
        const int b = tok >> 11, t = tok & 2047;
        const float* src = z + (size_t)b * DIMD * TT + t;
        const int d0 = wave * 128;
        zp = 0.0;
        f16_t* arow = As + lane * DIMD;
        const int x7 = lane & 7;
        for (int j = 0; j < 16; ++j) {
            f16x8 o;
            #pragma unroll
            for (int u = 0; u < 8; ++u) {
                float v = src[(size_t)(d0 + j * 8 + u) * TT];
                o[u] = (f16_t)v;
                float vv = v * v;
                zp += (double)vv;
            }
            *(f16x8*)(arow + (((wave * 16 + j) ^ x7) * 8)) = o;
        }
    }
    // zred handoff in Bs buf1 (overwritten only after the 2nd barrier below)
    float* zredp = (float*)(Bs + 4096);           // 4 x 64 floats
    zredp[wave * 64 + lane] = (float)zp;

    // ---- B staging bases: chunk = 128 codes x 32 d = 8KB, 2 gll16/thread ----
    const f16_t* gB[2]; f16_t* lB[2];
    #pragma unroll
    for (int q = 0; q < 2; ++q) {
        int s = q * 256 + tid;
        int row = s >> 2, p = s & 3;
        gB[q] = wf + (size_t)row * DIMD + (p ^ ((row >> 1) & 3)) * 8;
        lB[q] = Bs + s * 8;                    // + buf*4096 (f16 units)
    }
    // prologue: stage chunk 0 into buf 0
    gll16(gB[0], lB[0]);
    gll16(gB[1], lB[1]);
    __syncthreads();                            // A writes + zred + chunk0

    // z2 = fl32 sum of the 4 wave partials, left-to-right (== tsplit)
    if (wave == 0)
        z2[tok0 + lane] = ((zredp[lane] + zredp[64 + lane]) + zredp[128 + lane])
                          + zredp[192 + lane];
    __syncthreads();                            // protect buf1 until read done

    float b1[8], b2[8]; int i1[8];
    #pragma unroll
    for (int r = 0; r < 8; ++r) { b1[r] = 3.4e38f; b2[r] = 3.4e38f; i1[r] = 0; }

    // read-side constants
    const int a7 = m & 7;
    const f16_t* Arow0 = As + (rh * 32 + m) * DIMD;   // + mt*16*DIMD
    const int bq = (quad ^ ((m >> 1) & 3)) * 8;       // B read group, all nt
    const int br = chh * 64 + m;                      // + nt*16; row stride 32 f16

    for (int ct = 0; ct < 8; ++ct) {
        f32x4 acc[2][4] = {};
        #pragma unroll
        for (int dcc = 0; dcc < 16; ++dcc) {
            const int n = ct * 16 + dcc;
            // phase 1: issue next chunk's staging into the other buffer
            if (n + 1 < 128) {
                const int nct = (n + 1) >> 4, ndc = (n + 1) & 15;
                const size_t off = (size_t)nct * (128 * DIMD) + (size_t)ndc * 32;
                const int wb = (n + 1) & 1;
                gll16(gB[0] + off, lB[0] + wb * 4096);
                gll16(gB[1] + off, lB[1] + wb * 4096);
            }
            // phase 2: compute current chunk (K = dcc*32 .. +32, ascending)
            {
                const f16_t* Bc = Bs + (n & 1) * 4096;
                const int aswz = ((dcc * 4 + quad) ^ a7) * 8;
                f16x8 af0 = *(const f16x8*)(Arow0 + aswz);
                f16x8 af1 = *(const f16x8*)(Arow0 + 16 * DIMD + aswz);
                f16x8 bf0 = *(const f16x8*)(Bc + (br +  0) * 32 + bq);
                f16x8 bf1 = *(const f16x8*)(Bc + (br + 16) * 32 + bq);
                f16x8 bf2 = *(const f16x8*)(Bc + (br + 32) * 32 + bq);
                f16x8 bf3 = *(const f16x8*)(Bc + (br + 48) * 32 + bq);
                __builtin_amdgcn_s_setprio(1);
                acc[0][0] = __builtin_amdgcn_mfma_f32_16x16x32_f16(af0, bf0, acc[0][0], 0, 0, 0);
                acc[0][1] = __builtin_amdgcn_mfma_f32_16x16x32_f16(af0, bf1, acc[0][1], 0, 0, 0);
                acc[0][2] = __builtin_amdgcn_mfma_f32_16x16x32_f16(af0, bf2, acc[0][2], 0, 0, 0);
                acc[0][3] = __builtin_amdgcn_mfma_f32_16x16x32_f16(af0, bf3, acc[0][3], 0, 0, 0);
                acc[1][0] = __builtin_amdgcn_mfma_f32_16x16x32_f16(af1, bf0, acc[1][0], 0, 0, 0);
                acc[1][1] = __builtin_amdgcn_mfma_f32_16x16x32_f16(af1, bf1, acc[1][1], 0, 0, 0);
                acc[1][2] = __builtin_amdgcn_mfma_f32_16x16x32_f16(af1, bf2, acc[1][2], 0, 0, 0);
                acc[1][3] = __builtin_amdgcn_mfma_f32_16x16x32_f16(af1, bf3, acc[1][3], 0, 0, 0);
                __builtin_amdgcn_s_setprio(0);
            }
            __syncthreads();   // drains staging + releases consumed buffer
        }
        // ---- ct epilogue: tracker update (w2 from global, L2-hot 4KB) ----
        #pragma unroll
        for (int nt = 0; nt < 4; ++nt) {
            const int col = ct * 128 + chh * 64 + nt * 16 + m;
            const float w2c = w2[col];
            #pragma unroll
            for (int mt = 0; mt < 2; ++mt)
                #pragma unroll
                for (int r = 0; r < 4; ++r) {
                    float s = fmaf(NEG2_SCALE, acc[mt][nt][r], w2c);
                    const int ri = mt * 4 + r;
                    if (s < b1[ri]) { b2[ri] = b1[ri]; b1[ri] = s; i1[ri] = col; }
                    else if (s < b2[ri]) b2[ri] = s;
                }
        }
    }

    // reduce over the 16 m-lanes (code dimension within fragment)
    #pragma unroll
    for (int msk = 1; msk < 16; msk <<= 1) {
        #pragma unroll
        for (int ri = 0; ri < 8; ++ri) {
            float o1 = __shfl_xor(b1[ri], msk, 64);
            int   oi = __shfl_xor(i1[ri], msk, 64);
            float o2 = __shfl_xor(b2[ri], msk, 64);
            if (o1 < b1[ri] || (o1 == b1[ri] && oi < i1[ri])) {
                b2[ri] = fminf(b1[ri], o2); b1[ri] = o1; i1[ri] = oi;
            } else {
                b2[ri] = fminf(b2[ri], o1);
            }
        }
    }

    // merge the two code-halves (chh) via LDS scratch reusing As
    float* Lb1 = (float*)As;           // 64 floats
    float* Lb2 = Lb1 + 64;
    int*   Li  = (int*)(Lb2 + 64);
    if (chh == 1 && m == 0) {
        #pragma unroll
        for (int ri = 0; ri < 8; ++ri) {
            int row = rh * 32 + (ri >> 2) * 16 + quad * 4 + (ri & 3);
            Lb1[row] = b1[ri]; Lb2[row] = b2[ri]; Li[row] = i1[ri];
        }
    }
    __syncthreads();
    if (chh == 0 && m == 0) {
        #pragma unroll
        for (int ri = 0; ri < 8; ++ri) {
            int row = rh * 32 + (ri >> 2) * 16 + quad * 4 + (ri & 3);
            float o1 = Lb1[row], o2 = Lb2[row]; int oi = Li[row];
            if (o1 < b1[ri] || (o1 == b1[ri] && oi < i1[ri])) {
                b2[ri] = fminf(b1[ri], o2); b1[ri] = o1; i1[ri] = oi;
            } else {
                b2[ri] = fminf(b2[ri], o1);
            }
            int tok = tok0 + row;
            out_idx_f[tok] = (float)i1[ri];
            score[tok] = b1[ri];           // w2[k*] - 2*dot  (loss term)
            if (b2[ri] - b1[ri] <= TAU) {
                int p = atomicAdd(cnt, 1);
                list[p] = tok;
            }
        }
    }
}

// ---------- exact np-emulating recheck v2: 8 rows per block, 512 threads ----------
// Thread owns 2 CONSECUTIVE codes (k0=tid*2) read coalesced from cbT[d][k];
// each (row,code) f64 chain sums d-ascending with the identical 4-FMA group
// order as the validated kernel -> bitwise-same scores; argmin merge keeps
// smallest index at every level (thread j-order, lane shuffle, wave order).
__global__ __launch_bounds__(512) void recheck_kernel(
    const float* __restrict__ z, const float* __restrict__ cbT,
    const float* __restrict__ w2, const int* __restrict__ cnt,
    const int* __restrict__ list, float* __restrict__ out_idx_f)
{
    __shared__ float zrow[8][DIMD];    // 16KB
    __shared__ float z2s[8];
    __shared__ float rv[8][8];         // [wave][row]
    __shared__ int   ri[8][8];

    const int tid  = threadIdx.x;      // 0..511
    const int wave = tid >> 6;         // 0..7
    const int lane = tid & 63;
    const int total = *cnt;
    const int ngrp = (total + 7) >> 3;
    const int k0 = tid * 2;

    for (int g = blockIdx.x; g < ngrp; g += gridDim.x) {
        __syncthreads();
        const int nrows = min(8, total - g * 8);
        {
            int idx = g * 8 + wave;
            int tok = (idx < total) ? list[idx] : list[g * 8];
            int b = tok >> 11, t = tok & 2047;
            const float* zb = z + (size_t)b * DIMD * TT + t;
            double zp = 0.0;
            #pragma unroll
            for (int j = 0; j < 8; ++j) {
                int d = lane + 64 * j;
                float v = zb[(size_t)d * TT];
                zrow[wave][d] = v;
                float vv = v * v;
                zp += (double)vv;
            }
            #pragma unroll
            for (int msk = 1; msk < 64; msk <<= 1) zp += __shfl_xor(zp, msk, 64);
            if (lane == 0) z2s[wave] = (float)zp;
        }
        __syncthreads();

        double acc[8][2] = {};   // [row][code]
        // prefetch double-buffer over d (f32x2: this thread's 2 codes)
        f32x2 cw0 = *(const f32x2*)(cbT + (size_t)0 * KCB + k0);
        f32x2 cw1 = *(const f32x2*)(cbT + (size_t)1 * KCB + k0);
        f32x2 cw2 = *(const f32x2*)(cbT + (size_t)2 * KCB + k0);
        f32x2 cw3 = *(const f32x2*)(cbT + (size_t)3 * KCB + k0);
        for (int d = 0; d < DIMD; d += 4) {
            f32x2 n0, n1, n2, n3;
            if (d + 4 < DIMD) {
                n0 = *(const f32x2*)(cbT + (size_t)(d + 4) * KCB + k0);
                n1 = *(const f32x2*)(cbT + (size_t)(d + 5) * KCB + k0);
                n2 = *(const f32x2*)(cbT + (size_t)(d + 6) * KCB + k0);
                n3 = *(const f32x2*)(cbT + (size_t)(d + 7) * KCB + k0);
            }
            #pragma unroll
            for (int r = 0; r < 8; ++r) {
                f32x4 zv = *(const f32x4*)&zrow[r][d];
                #pragma unroll
                for (int j = 0; j < 2; ++j) {
                    acc[r][j] = fma((double)zv[0], (double)cw0[j], acc[r][j]);
                    acc[r][j] = fma((double)zv[1], (double)cw1[j], acc[r][j]);
                    acc[r][j] = fma((double)zv[2], (double)cw2[j], acc[r][j]);
                    acc[r][j] = fma((double)zv[3], (double)cw3[j], acc[r][j]);
                }
            }
            cw0 = n0; cw1 = n1; cw2 = n2; cw3 = n3;
        }

        f32x2 w2q = *(const f32x2*)(w2 + k0);
        float bv[8]; int bi[8];
        #pragma unroll
        for (int r = 0; r < 8; ++r) { bv[r] = 3.4e38f; bi[r] = 0; }
        #pragma unroll
        for (int r = 0; r < 8; ++r)
            #pragma unroll
            for (int j = 0; j < 2; ++j) {
                float dotf = (float)acc[r][j];
                float t2   = z2s[r] - 2.0f * dotf;
                float s    = t2 + w2q[j];
                // j ascending => ties keep smaller k automatically
                if (s < bv[r]) { bv[r] = s; bi[r] = k0 + j; }
            }
        #pragma unroll
        for (int msk = 1; msk < 64; msk <<= 1) {
            #pragma unroll
            for (int r = 0; r < 8; ++r) {
                float ov = __shfl_xor(bv[r], msk, 64);
                int   oi = __shfl_xor(bi[r], msk, 64);
                if (ov < bv[r] || (ov == bv[r] && oi < bi[r])) { bv[r] = ov; bi[r] = oi; }
            }
        }
        if (lane == 0) {
            #pragma unroll
            for (int r = 0; r < 8; ++r) { rv[wave][r] = bv[r]; ri[wave][r] = bi[r]; }
        }
        __syncthreads();
        if (tid < 8) {
            float v = rv[0][tid]; int k = ri[0][tid];
            #pragma unroll
            for (int w = 1; w < 8; ++w) {
                if (rv[w][tid] < v || (rv[w][tid] == v && ri[w][tid] < k)) {
                    v = rv[w][tid]; k = ri[w][tid];
                }
            }
            if (tid < nrows) out_idx_f[list[g * 8 + tid]] = (float)k;
        }
    }
}

// ---------- gather v2: LDS-staged coalesced copy; + loss folded (blocks<32) --
// 512 blocks x 64 tokens. cb rows read coalesced (f32x4), LDS transpose with
// stride-65 pad (2-way banks = free), 256B-contiguous output chunks.
#define GLDS_BYTES (512 * 65 * 4 + 256)
__global__ __launch_bounds__(256) void gather_kernel(
    const float* __restrict__ cb, const float* __restrict__ idx_f,
    const float* __restrict__ z2, const float* __restrict__ score,
    float* __restrict__ out, float* __restrict__ loss)
{
    extern __shared__ __align__(16) char gsm[];
    float* zqT = (float*)gsm;                  // [512 d][65] floats
    int*   ki  = (int*)(gsm + 512 * 65 * 4);   // 64 ints

    const int tid  = threadIdx.x;
    const int wave = tid >> 6, lane = tid & 63;
    const int tok0 = blockIdx.x * 64;
    const int bidx = tok0 >> 11;
    const int t0   = tok0 & 2047;

    if (tid < 64) ki[tid] = (int)(idx_f[tok0 + tid] + 0.5f);
    __syncthreads();

    // load 16 rows per wave (coalesced f32x4), scatter into transposed LDS
    for (int jj = 0; jj < 16; ++jj) {
        const int j = wave * 16 + jj;
        const float* crow = cb + (size_t)ki[j] * DIMD;
        #pragma unroll
        for (int seg = 0; seg < 2; ++seg) {
            const int d = seg * 256 + lane * 4;
            f32x4 v = *(const f32x4*)(crow + d);
            zqT[(d + 0) * 65 + j] = v[0];
            zqT[(d + 1) * 65 + j] = v[1];
            zqT[(d + 2) * 65 + j] = v[2];
            zqT[(d + 3) * 65 + j] = v[3];
        }
    }
    __syncthreads();

    // write out: thread -> (d = it*16 + tid>>4, 4 consecutive t)
    float* obase = out + (size_t)bidx * DIMD * TT + t0;
    for (int it = 0; it < 32; ++it) {
        const int d  = it * 16 + (tid >> 4);
        const int j4 = (tid & 15) * 4;
        const float* zr = &zqT[d * 65 + j4];
        f32x4 v; v[0] = zr[0]; v[1] = zr[1]; v[2] = zr[2]; v[3] = zr[3];
        *(f32x4*)(obase + (size_t)d * TT + j4) = v;
    }

    // ---- loss fold-in: blocks 0..31, 1024 tokens each ----
    if (blockIdx.x < 32) {
        __syncthreads();
        double* red = (double*)gsm;
        const int idx = blockIdx.x * 1024 + tid * 4;
        float4 a = *(const float4*)(z2 + idx);
        float4 s = *(const float4*)(score + idx);
        double part = ((double)a.x + (double)s.x) + ((double)a.y + (double)s.y) +
                      ((double)a.z + (double)s.z) + ((double)a.w + (double)s.w);
        #pragma unroll
        for (int mm = 1; mm < 64; mm <<= 1) part += __shfl_xor(part, mm, 64);
        if (lane == 0) red[wave] = part;
        __syncthreads();
        if (tid == 0) {
            double tot = red[0] + red[1] + red[2] + red[3];
            atomicAdd(loss, (float)(tot * (1.25 / (double)(BB * DIMD * TT))));
        }
    }
}

extern "C" void kernel_launch(void* const* d_in, const int* in_sizes, int n_in,
                              void* d_out, int out_size, void* d_ws, size_t ws_size,
                              hipStream_t stream) {
    const float* z  = (const float*)d_in[0];
    const float* cb = (const float*)d_in[1];
    float* out = (float*)d_out;

    // cbT (2MB fp32 transposed codebook) parked inside the z_q_st output
    // region at +33MB; consumed by recheck before gather overwrites out.
    float* cbT = (float*)((char*)out + (33u << 20));

    char* wsb = (char*)d_ws;
    f16_t* wf    = (f16_t*)wsb;                         // 1 MB
    float* w2    = (float*)(wsb + (1 << 20));           // 4 KB
    int*   cnt   = (int*)(wsb + (1 << 20) + 4096);
    int*   list  = (int*)(wsb + (1 << 20) + 8192);      // 128 KB
    float* z2    = (float*)(wsb + (1 << 20) + 8192 + (128 << 10));   // 128 KB
    float* score = z2 + NTOT;                           // 128 KB

    hipMemsetAsync(out + OUT_LOSS, 0, sizeof(float), stream);
    hipMemsetAsync(cnt, 0, sizeof(int), stream);
    prep_kernel<<<KCB / 4, 256, 0, stream>>>(cb, wf, w2, cbT);
    fast_kernel<<<NTOT / BTOK, 256, 80 << 10, stream>>>(
        z, wf, w2, out + OUT_IDX, score, z2, cnt, list);
    recheck_kernel<<<512, 512, 0, stream>>>(z, cbT, w2, cnt, list, out + OUT_IDX);
    gather_kernel<<<NTOT / 64, 256, GLDS_BYTES, stream>>>(
        cb, out + OUT_IDX, z2, score, out, out + OUT_LOSS);
}